// Round 2
// baseline (3338.156 us; speedup 1.0000x reference)
//
#include <hip/hip_runtime.h>
#include <math.h>

// Problem constants (from reference)
#define NN 50000      // nodes
#define NE 200000     // edges
#define NH 4          // heads
#define NG 100        // graphs
#define EPSBN 1e-5f
#define SLOPE 0.2f

// ---- ordered-uint mapping for float atomicMax ----
__device__ __forceinline__ unsigned fmap(float f) {
    unsigned u = __float_as_uint(f);
    return (u & 0x80000000u) ? ~u : (u | 0x80000000u);
}
__device__ __forceinline__ float funmap(unsigned u) {
    return (u & 0x80000000u) ? __uint_as_float(u & 0x7fffffffu)
                             : __uint_as_float(~u);
}

__global__ void fill_val(float* p, int n, float v) {
    int i = blockIdx.x * 256 + threadIdx.x;
    if (i < n) p[i] = v;
}

// ---------- f32 tiled GEMM: C[M,N] (= or +=) A[M,K] @ B[K,N] (+ bias[N]) ----------
// B has leading dim ldb (column-slice support). 128x128 tile, 256 thr, 8x8/thread.
template<int BM, int BN, int BK, bool INIT>
__launch_bounds__(256)
__global__ void gemm_bias(const float* __restrict__ A, const float* __restrict__ B,
                          const float* __restrict__ bias, float* __restrict__ C,
                          int M, int N, int K, int ldb) {
    __shared__ float As[BK][BM + 4];   // A transposed: As[k][m]
    __shared__ float Bs[BK][BN + 4];
    const int tid = threadIdx.x;
    const int tx = tid & 15, ty = tid >> 4;
    const int m0 = blockIdx.x * BM, n0 = blockIdx.y * BN;
    float acc[8][8];
#pragma unroll
    for (int i = 0; i < 8; ++i)
#pragma unroll
        for (int j = 0; j < 8; ++j) acc[i][j] = 0.f;

    for (int k0 = 0; k0 < K; k0 += BK) {
#pragma unroll
        for (int t = tid; t < BM * BK / 4; t += 256) {
            int r = t / (BK / 4);
            int c = (t % (BK / 4)) * 4;
            float4 v = make_float4(0.f, 0.f, 0.f, 0.f);
            if (m0 + r < M)
                v = *(const float4*)&A[(size_t)(m0 + r) * K + k0 + c];
            As[c + 0][r] = v.x; As[c + 1][r] = v.y;
            As[c + 2][r] = v.z; As[c + 3][r] = v.w;
        }
#pragma unroll
        for (int t = tid; t < BK * BN / 4; t += 256) {
            int r = t / (BN / 4);
            int c = (t % (BN / 4)) * 4;
            *(float4*)&Bs[r][c] = *(const float4*)&B[(size_t)(k0 + r) * ldb + n0 + c];
        }
        __syncthreads();
#pragma unroll
        for (int kk = 0; kk < BK; ++kk) {
            float a[8], b[8];
            *(float4*)&a[0] = *(const float4*)&As[kk][ty * 8];
            *(float4*)&a[4] = *(const float4*)&As[kk][ty * 8 + 4];
            *(float4*)&b[0] = *(const float4*)&Bs[kk][tx * 8];
            *(float4*)&b[4] = *(const float4*)&Bs[kk][tx * 8 + 4];
#pragma unroll
            for (int i = 0; i < 8; ++i)
#pragma unroll
                for (int j = 0; j < 8; ++j)
                    acc[i][j] = fmaf(a[i], b[j], acc[i][j]);
        }
        __syncthreads();
    }
#pragma unroll
    for (int i = 0; i < 8; ++i) {
        int m = m0 + ty * 8 + i;
        if (m >= M) continue;
#pragma unroll
        for (int j = 0; j < 8; j += 4) {
            int n = n0 + tx * 8 + j;
            float4 v;
            if (INIT) {
                v.x = acc[i][j + 0] + bias[n + 0];
                v.y = acc[i][j + 1] + bias[n + 1];
                v.z = acc[i][j + 2] + bias[n + 2];
                v.w = acc[i][j + 3] + bias[n + 3];
            } else {
                float4 o = *(const float4*)&C[(size_t)m * N + n];
                v.x = o.x + acc[i][j + 0];
                v.y = o.y + acc[i][j + 1];
                v.z = o.z + acc[i][j + 2];
                v.w = o.w + acc[i][j + 3];
            }
            *(float4*)&C[(size_t)m * N + n] = v;
        }
    }
}

// ---------- pass A: per-edge logits + segment max ----------
// one 64-lane wave per edge; 16 edges per 1024-thread block; We slice in LDS.
// HC = width of xl/xr rows; NHEADS heads in this pass; C = HC/NHEADS.
template<int HC, int NHEADS>
__launch_bounds__(1024)
__global__ void edge_logits(const float* __restrict__ xl, const float* __restrict__ xr,
                            const int* __restrict__ ei, const float* __restrict__ ea,
                            const float* __restrict__ We, int ldwe,
                            const float* __restrict__ att,
                            float* __restrict__ lg, unsigned* __restrict__ mx) {
    __shared__ float sWe[12 * HC];
    for (int t = threadIdx.x * 4; t < 12 * HC; t += 1024 * 4) {
        int r = t / HC, c = t % HC;
        *(float4*)&sWe[t] = *(const float4*)&We[(size_t)r * ldwe + c];
    }
    __syncthreads();
    const int e = blockIdx.x * 16 + (threadIdx.x >> 6);
    const int lane = threadIdx.x & 63;
    if (e >= NE) return;
    const int src = ei[e], dst = ei[NE + e];
    float eav[12];
#pragma unroll
    for (int d = 0; d < 12; ++d) eav[d] = ea[(size_t)e * 12 + d];
    const float* xls = xl + (size_t)src * HC;
    const float* xrs = xr + (size_t)dst * HC;
    float part[NHEADS];
#pragma unroll
    for (int h = 0; h < NHEADS; ++h) part[h] = 0.f;
#pragma unroll
    for (int i = 0; i < HC / 64; ++i) {
        int cf = lane + 64 * i;
        float ecf = 0.f;
#pragma unroll
        for (int d = 0; d < 12; ++d) ecf = fmaf(eav[d], sWe[d * HC + cf], ecf);
        float mv = xls[cf] + xrs[cf] + ecf;      // xl[src]+xr[dst]+e
        mv = mv > 0.f ? mv : SLOPE * mv;         // leaky_relu
        const int h = (64 * i * NHEADS) / HC;    // head of this 64-lane chunk
        part[h] = fmaf(mv, att[cf], part[h]);
    }
#pragma unroll
    for (int h = 0; h < NHEADS; ++h) {
        float v = part[h];
#pragma unroll
        for (int off = 32; off > 0; off >>= 1) v += __shfl_xor(v, off);
        if (lane == 0) {
            lg[(size_t)e * NHEADS + h] = v;
            atomicMax(&mx[(size_t)dst * NHEADS + h], fmap(v));
        }
    }
}

// ---------- pass B: ex = exp(logit - mx[dst]); den[dst] += ex ----------
template<int NHEADS>
__global__ void edge_exp(const int* __restrict__ ei, float* __restrict__ lg,
                         const unsigned* __restrict__ mx, float* __restrict__ den) {
    int idx = blockIdx.x * 256 + threadIdx.x;
    if (idx >= NE * NHEADS) return;
    int e = idx / NHEADS, h = idx % NHEADS;
    int dst = ei[NE + e];
    float v = __expf(lg[idx] - funmap(mx[(size_t)dst * NHEADS + h]));
    lg[idx] = v;   // store ex over logits
    unsafeAtomicAdd(&den[(size_t)dst * NHEADS + h], v);
}

// ---------- pass C: agg[dst] += xl[src] * alpha ----------
template<int HC, int NHEADS>
__launch_bounds__(256)
__global__ void edge_aggregate(const float* __restrict__ xl, const int* __restrict__ ei,
                               const float* __restrict__ ex, const float* __restrict__ den,
                               float* __restrict__ agg) {
    const int e = blockIdx.x * 4 + (threadIdx.x >> 6);
    if (e >= NE) return;
    const int lane = threadIdx.x & 63;
    const int src = ei[e], dst = ei[NE + e];
    float alpha[NHEADS];
#pragma unroll
    for (int h = 0; h < NHEADS; ++h)
        alpha[h] = ex[(size_t)e * NHEADS + h] / (den[(size_t)dst * NHEADS + h] + 1e-16f);
    const float* xls = xl + (size_t)src * HC;
    float* aggd = agg + (size_t)dst * HC;
#pragma unroll
    for (int i = 0; i < HC / 64; ++i) {
        int cf = lane + 64 * i;
        const int h = (64 * i * NHEADS) / HC;
        unsafeAtomicAdd(&aggd[cf], xls[cf] * alpha[h]);
    }
}

// ---------- h = bn(relu(h + bias)) elementwise, in place ----------
__global__ void bias_relu_bn(float* __restrict__ h, const float* __restrict__ b,
                             const float* __restrict__ gam, const float* __restrict__ bet,
                             const float* __restrict__ mu, const float* __restrict__ var,
                             int hcMask, size_t total4) {
    size_t i = (size_t)blockIdx.x * 256 + threadIdx.x;
    if (i >= total4) return;
    float4 x = ((float4*)h)[i];
    int c = (int)((i * 4) & (size_t)hcMask);
    float* xp = &x.x;
#pragma unroll
    for (int j = 0; j < 4; ++j) {
        float t = xp[j] + b[c + j];
        t = fmaxf(t, 0.f);
        xp[j] = (t - mu[c + j]) * rsqrtf(var[c + j] + EPSBN) * gam[c + j] + bet[c + j];
    }
    ((float4*)h)[i] = x;
}

// ---------- head: master = h2[cumsum(n_nodes)-1]; relu(master@Wf1+bf1)@Wf2+bf2 ----------
__launch_bounds__(64)
__global__ void head_mlp(const float* __restrict__ h2, const int* __restrict__ n_nodes,
                         const float* __restrict__ Wf1, const float* __restrict__ bf1,
                         const float* __restrict__ Wf2, const float* __restrict__ bf2,
                         float* __restrict__ out) {
    const int g = blockIdx.x;
    const int t = threadIdx.x;   // 64 threads = 1 wave
    int acc = 0;
    for (int i = t; i <= g; i += 64) acc += n_nodes[i];
#pragma unroll
    for (int off = 32; off > 0; off >>= 1) acc += __shfl_xor(acc, off);
    const int node = acc - 1;
    __shared__ float row[256];
    for (int i = t; i < 256; i += 64) row[i] = h2[(size_t)node * 256 + i];
    __syncthreads();
    float hid = bf1[t];
    for (int k = 0; k < 256; ++k) hid = fmaf(row[k], Wf1[k * 64 + t], hid);
    hid = fmaxf(hid, 0.f);
    float p = hid * Wf2[t];
#pragma unroll
    for (int off = 32; off > 0; off >>= 1) p += __shfl_xor(p, off);
    if (t == 0) out[g] = p + bf2[0];
}

extern "C" void kernel_launch(void* const* d_in, const int* in_sizes, int n_in,
                              void* d_out, int out_size, void* d_ws, size_t ws_size,
                              hipStream_t stream) {
    const float* x   = (const float*)d_in[0];
    const int*   ei  = (const int*)d_in[1];
    const float* ea  = (const float*)d_in[2];
    const int*   nnd = (const int*)d_in[3];
    const float* Wl1 = (const float*)d_in[4];
    const float* bl1 = (const float*)d_in[5];
    const float* Wr1 = (const float*)d_in[6];
    const float* br1 = (const float*)d_in[7];
    const float* We1 = (const float*)d_in[8];
    const float* att1= (const float*)d_in[9];
    const float* b1  = (const float*)d_in[10];
    const float* g1  = (const float*)d_in[11];
    const float* be1 = (const float*)d_in[12];
    const float* m1  = (const float*)d_in[13];
    const float* v1  = (const float*)d_in[14];
    const float* Wl2 = (const float*)d_in[15];
    const float* bl2 = (const float*)d_in[16];
    const float* Wr2 = (const float*)d_in[17];
    const float* br2 = (const float*)d_in[18];
    const float* We2 = (const float*)d_in[19];
    const float* att2= (const float*)d_in[20];
    const float* b2  = (const float*)d_in[21];
    const float* g2  = (const float*)d_in[22];
    const float* be2 = (const float*)d_in[23];
    const float* m2  = (const float*)d_in[24];
    const float* v2  = (const float*)d_in[25];
    const float* Wf1 = (const float*)d_in[26];
    const float* bf1 = (const float*)d_in[27];
    const float* Wf2 = (const float*)d_in[28];
    const float* bf2 = (const float*)d_in[29];
    float* out = (float*)d_out;

    // workspace layout: 4 x [N,256] f32 panels + lg + mx + den  (~209.6 MB)
    const size_t PB = (size_t)NN * 256 * sizeof(float);   // 51.2 MB
    char* ws = (char*)d_ws;
    float*    buf0 = (float*)ws;               // xl_h (L1) ; unused in L2
    float*    buf1 = (float*)(ws + PB);        // xr_h -> agg_h -> h1_h (L1)
    float*    xl2  = (float*)(ws + 2 * PB);
    float*    xr2  = (float*)(ws + 3 * PB);    // -> agg2 -> h2 (L2)
    float*    lg   = (float*)(ws + 4 * PB);                          // [E,4] max
    unsigned* mx   = (unsigned*)(ws + 4 * PB + (size_t)NE * NH * 4); // [N,4] max
    float*    den  = (float*)(ws + 4 * PB + (size_t)NE * NH * 4 + (size_t)NN * NH * 4);
    const size_t needed = 4 * PB + (size_t)NE * NH * 4 + 2 * (size_t)NN * NH * 4;
    if (ws_size < needed) {
        // diagnostic sentinel: absmax ~1e30 next round => workspace still too small
        fill_val<<<(out_size + 255) / 256, dim3(256), 0, stream>>>(out, out_size, 1e30f);
        return;
    }

    const dim3 B256(256), B1024(1024), B64(64);
    const dim3 gemmGrid((NN + 127) / 128, 2);   // N=256 => 2 column tiles

    // ================= layer 1, per head (separable) =================
    for (int h = 0; h < NH; ++h) {
        // xl_h = x @ Wl1[:, h*256:(h+1)*256] + bl1[h*256:...]  (ldb = 1024)
        gemm_bias<128,128,32,true><<<gemmGrid, B256, 0, stream>>>(
            x, Wl1 + h * 256, bl1 + h * 256, buf0, NN, 256, 256, 1024);
        gemm_bias<128,128,32,true><<<gemmGrid, B256, 0, stream>>>(
            x, Wr1 + h * 256, br1 + h * 256, buf1, NN, 256, 256, 1024);

        hipMemsetAsync(mx, 0, (size_t)NN * 4, stream);
        edge_logits<256,1><<<NE / 16, B1024, 0, stream>>>(
            buf0, buf1, ei, ea, We1 + h * 256, 1024, att1 + h * 256, lg, mx);
        hipMemsetAsync(den, 0, (size_t)NN * 4, stream);
        edge_exp<1><<<(NE + 255) / 256, B256, 0, stream>>>(ei, lg, mx, den);
        hipMemsetAsync(buf1, 0, PB, stream);   // xr_h dead after pass A -> agg_h
        edge_aggregate<256,1><<<NE / 4, B256, 0, stream>>>(buf0, ei, lg, den, buf1);
        bias_relu_bn<<<(unsigned)((PB / 16 + 255) / 256), B256, 0, stream>>>(
            buf1, b1 + h * 256, g1 + h * 256, be1 + h * 256, m1 + h * 256, v1 + h * 256,
            255, PB / 16);

        // partial-K accumulation into layer-2 transforms:
        // xl2 (h==0: = bias) += h1_h @ Wl2[h*256:(h+1)*256, :]
        if (h == 0) {
            gemm_bias<128,128,32,true><<<gemmGrid, B256, 0, stream>>>(
                buf1, Wl2 + (size_t)h * 256 * 256, bl2, xl2, NN, 256, 256, 256);
            gemm_bias<128,128,32,true><<<gemmGrid, B256, 0, stream>>>(
                buf1, Wr2 + (size_t)h * 256 * 256, br2, xr2, NN, 256, 256, 256);
        } else {
            gemm_bias<128,128,32,false><<<gemmGrid, B256, 0, stream>>>(
                buf1, Wl2 + (size_t)h * 256 * 256, nullptr, xl2, NN, 256, 256, 256);
            gemm_bias<128,128,32,false><<<gemmGrid, B256, 0, stream>>>(
                buf1, Wr2 + (size_t)h * 256 * 256, nullptr, xr2, NN, 256, 256, 256);
        }
    }

    // ================= layer 2 (HC=256, 4 heads at once) =================
    hipMemsetAsync(mx, 0, (size_t)NN * NH * 4, stream);
    edge_logits<256,4><<<NE / 16, B1024, 0, stream>>>(
        xl2, xr2, ei, ea, We2, 256, att2, lg, mx);
    hipMemsetAsync(den, 0, (size_t)NN * NH * 4, stream);
    edge_exp<4><<<(NE * NH + 255) / 256, B256, 0, stream>>>(ei, lg, mx, den);
    hipMemsetAsync(buf0, 0, PB, stream);   // agg2
    edge_aggregate<256,4><<<NE / 4, B256, 0, stream>>>(xl2, ei, lg, den, buf0);
    bias_relu_bn<<<(unsigned)((PB / 16 + 255) / 256), B256, 0, stream>>>(
        buf0, b2, g2, be2, m2, v2, 255, PB / 16);

    // ================= head MLP =================
    head_mlp<<<NG, B64, 0, stream>>>(buf0, nnd, Wf1, bf1, Wf2, bf2, out);
}